// Round 5
// baseline (354.749 us; speedup 1.0000x reference)
//
#include <hip/hip_runtime.h>
#include <stdint.h>

// ---------------------------------------------------------------- constants
#define NB     8192     // batch
#define NF     256      // features
#define NHALF  128      // F/2
#define NHID   512      // hidden = 2F
#define NLAY   4        // coupling layers
#define NK     32768    // codebook size

typedef __attribute__((ext_vector_type(8))) short bf16x8;   // 8 bf16 = 4 VGPR
typedef __attribute__((ext_vector_type(4))) float f32x4;

static __device__ __forceinline__ unsigned short f2bf(float f) {
  union { float f; unsigned int u; } v; v.f = f;
  return (unsigned short)((v.u + 0x7FFFu + ((v.u >> 16) & 1u)) >> 16);  // RNE
}
static __device__ __forceinline__ float bf2f(unsigned short u) {
  union { unsigned int u; float f; } v; v.u = ((unsigned int)u) << 16; return v.f;
}

// async global->LDS, 16B per lane; LDS dest = wave-uniform base + lane*16
static __device__ __forceinline__ void load_lds16(const void* g, void* l) {
  __builtin_amdgcn_global_load_lds(
      (const __attribute__((address_space(1))) unsigned int*)g,
      (__attribute__((address_space(3))) unsigned int*)l, 16, 0, 0);
}

// pack (score, idx) so u64 max == argmax with smallest-index tiebreak
static __device__ __forceinline__ unsigned long long packsi(float v, int idx) {
  unsigned int b = __float_as_uint(v);
  b = (b & 0x80000000u) ? ~b : (b | 0x80000000u);   // order-preserving map
  return ((unsigned long long)b << 32) | (unsigned int)(~(unsigned int)idx);
}

static __device__ __forceinline__ float fast_tanh(float x) {
  const float xc = fminf(fmaxf(x, -15.f), 15.f);
  const float e2 = __expf(2.f * xc);
  return 1.f - 2.f / (e2 + 1.f);
}

// LDS tile address: [kseg][row][64 shorts], 3-bit XOR chunk swizzle.
// Proven 0-conflict (R2/R4 evidence) for ds_read_b128 with 16 lanes on rows.
static __device__ __forceinline__ int swadr(int kseg, int nrows, int row, int kin) {
  return (kseg * nrows + row) * 64 + (((kin >> 3) ^ (row & 7)) * 8) + (kin & 7);
}

// ---------------------------------------------------------------- fused flow (ALL 4 layers)
// One block = 32 batch rows, grid 256. The coupling recurrence is row-local:
// xb_{l+1} = xa_l, xa_{l+1} = yb_l -> two bf16 LDS buffers ping-pong, yb
// overwrites xb in place (reader == writer per element). h streams through an
// 8 KB LDS chunk; GEMM2 K-accumulates per chunk. jac in registers.
// fp32 outputs: yb_2 -> xout[:,128:] at l==2, yb_3 -> xout[:,:128] at l==3.
__global__ __launch_bounds__(256, 1)
void flow_all(const float* __restrict__ in,
              const unsigned short* __restrict__ W1T,   // [L][512][128]
              const unsigned short* __restrict__ W2I,   // [L][256][512] s/t interleaved
              const float* __restrict__ b1A,
              const float* __restrict__ bsA,
              const float* __restrict__ btA,
              float* __restrict__ xout,
              unsigned short* __restrict__ xfbf,
              float* __restrict__ jac)
{
  __shared__ __align__(16) unsigned short Xb[2][32 * 128];   // 16 KB x-state
  __shared__ __align__(16) unsigned short Hs[2 * 32 * 64];   //  8 KB h chunk
  __shared__ __align__(16) unsigned short Bs[2048 * 8];      // 32 KB W staging
  const int tid = threadIdx.x;
  const int lane = tid & 63, wave = tid >> 6;
  const int q = lane >> 4, c = lane & 15;
  const int m0 = blockIdx.x * 32;

  // ---- init: Xb[0] = bf16(in[:, :128]) (xa_0), Xb[1] = bf16(in[:, 128:]) (xb_0)
#pragma unroll
  for (int v = 0; v < 8; v++) {
    const int t4 = tid + v * 256;            // 2048 float4s = 32 rows x 64
    const int row = t4 >> 6, f4 = t4 & 63;
    const float4 d = *(const float4*)(in + (size_t)(m0 + row) * NF + f4 * 4);
    unsigned short* dst = Xb[f4 >> 5];
    const int feat = (f4 & 31) * 4;
    const float vals[4] = {d.x, d.y, d.z, d.w};
#pragma unroll
    for (int u = 0; u < 4; u++) {
      const int fe = feat + u;
      dst[swadr(fe >> 6, 32, row, fe & 63)] = f2bf(vals[u]);
    }
  }

  float jr[2][4];
#pragma unroll
  for (int i = 0; i < 2; i++)
#pragma unroll
    for (int r = 0; r < 4; r++) jr[i][r] = 0.f;

  for (int l = 0; l < NLAY; l++) {
    __syncthreads();                          // x-state writes visible
    const unsigned short* W1l = W1T + (size_t)l * NHID * NHALF;
    const unsigned short* W2l = W2I + (size_t)l * NF * NHID;
    const float* b1l = b1A + l * NHID;
    const float* bsl = bsA + l * NHALF;
    const float* btl = btA + l * NHALF;
    unsigned short* XA = Xb[l & 1];
    unsigned short* XB = Xb[1 - (l & 1)];

    // GEMM1 A-fragments from XA (LDS)
    bf16x8 af1[2][4];
#pragma unroll
    for (int i = 0; i < 2; i++) {
      const int row = 16 * i + c;
#pragma unroll
      for (int kw = 0; kw < 4; kw++) {
        const int kch = kw * 4 + q;
        af1[i][kw] = *(const bf16x8*)(XA + ((kch >> 3) * 32 + row) * 64 +
                                      (((kch & 7) ^ (row & 7)) * 8));
      }
    }

    const f32x4 z = {0.f, 0.f, 0.f, 0.f};
    f32x4 acc2[2][4];
#pragma unroll
    for (int i = 0; i < 2; i++)
#pragma unroll
      for (int j = 0; j < 4; j++) acc2[i][j] = z;

    for (int nc = 0; nc < 4; nc++) {
      __syncthreads();                        // Bs free
      // stage W1T[nc*128 .. +128][0..128] as [kseg2][128][64]
#pragma unroll
      for (int u = 0; u < 8; u++) {
        const int chb = (wave * 8 + u) * 64;
        const int ch = chb + lane;
        const int kseg = ch >> 10, cs = ch & 1023;
        const int row = cs >> 3, cc = (cs & 7) ^ (row & 7);
        load_lds16(W1l + (size_t)(nc * 128 + row) * NHALF + kseg * 64 + cc * 8,
                   Bs + chb * 8);
      }
      __syncthreads();

      f32x4 acc1[2][2];
#pragma unroll
      for (int i = 0; i < 2; i++)
#pragma unroll
        for (int j = 0; j < 2; j++) acc1[i][j] = z;

#pragma unroll
      for (int kw = 0; kw < 4; kw++) {
        const int kseg = kw >> 1, g = (kw & 1) * 4 + q;
#pragma unroll
        for (int j = 0; j < 2; j++) {
          const int rb = wave * 32 + 16 * j + c;
          const bf16x8 bf = *(const bf16x8*)(Bs + (kseg * 128 + rb) * 64 + ((g ^ (rb & 7)) * 8));
          acc1[0][j] = __builtin_amdgcn_mfma_f32_16x16x32_bf16(af1[0][kw], bf, acc1[0][j], 0, 0, 0);
          acc1[1][j] = __builtin_amdgcn_mfma_f32_16x16x32_bf16(af1[1][kw], bf, acc1[1][j], 0, 0, 0);
        }
      }
      // h chunk -> Hs [kseg2][32][64] (relu + bias)
#pragma unroll
      for (int i = 0; i < 2; i++)
#pragma unroll
        for (int j = 0; j < 2; j++) {
          const int hc = wave * 32 + 16 * j + c;      // 0..127 within chunk
          const float bb = b1l[nc * 128 + hc];
#pragma unroll
          for (int r = 0; r < 4; r++) {
            float v = acc1[i][j][r] + bb;
            v = v > 0.f ? v : 0.f;
            Hs[swadr(hc >> 6, 32, 16 * i + 4 * q + r, hc & 63)] = f2bf(v);
          }
        }

      for (int kt2 = 0; kt2 < 2; kt2++) {
        __syncthreads();                      // Hs ready / Bs free
        // stage W2I[0..256][nc*128 + kt2*64 .. +64] as [256][64]
#pragma unroll
        for (int u = 0; u < 8; u++) {
          const int chb = (wave * 8 + u) * 64;
          const int ch = chb + lane;
          const int row = ch >> 3, cc = (ch & 7) ^ (row & 7);
          load_lds16(W2l + (size_t)row * NHID + nc * 128 + kt2 * 64 + cc * 8,
                     Bs + chb * 8);
        }
        __syncthreads();
#pragma unroll
        for (int ks = 0; ks < 2; ks++) {
          const int g = ks * 4 + q;
          bf16x8 afh[2];
#pragma unroll
          for (int i = 0; i < 2; i++) {
            const int ra = 16 * i + c;
            afh[i] = *(const bf16x8*)(Hs + (kt2 * 32 + ra) * 64 + ((g ^ (ra & 7)) * 8));
          }
#pragma unroll
          for (int j = 0; j < 4; j++) {
            const int rb = wave * 64 + 16 * j + c;
            const bf16x8 bf = *(const bf16x8*)(Bs + rb * 64 + ((g ^ (rb & 7)) * 8));
            acc2[0][j] = __builtin_amdgcn_mfma_f32_16x16x32_bf16(afh[0], bf, acc2[0][j], 0, 0, 0);
            acc2[1][j] = __builtin_amdgcn_mfma_f32_16x16x32_bf16(afh[1], bf, acc2[1][j], 0, 0, 0);
          }
        }
      }
    }

    // ---- coupling epilogue (even col=s, odd col=t)
    const int parity = c & 1;
    const int lastl = (l == NLAY - 1);
#pragma unroll
    for (int i = 0; i < 2; i++)
#pragma unroll
      for (int j = 0; j < 4; j++) {
        const int col = wave * 64 + 16 * j + c;
#pragma unroll
        for (int r = 0; r < 4; r++) {
          const float val = acc2[i][j][r];
          const float oth = __shfl_xor(val, 1);     // all lanes participate
          if (!parity) {
            const int feat = col >> 1;
            float s = val + bsl[feat];
            if (!lastl) s = fast_tanh(s);
            const float t = oth + btl[feat];
            const int row = 16 * i + 4 * q + r;
            const int xaddr = swadr(feat >> 6, 32, row, feat & 63);
            const float xb = bf2f(XB[xaddr]);
            const float yb = xb * __expf(s) + t;
            jr[i][r] += s;
            XB[xaddr] = f2bf(yb);                   // in-place: same owner thread
            const size_t grow = (size_t)(m0 + row) * NF;
            if (l == 2) { xout[grow + NHALF + feat] = yb; xfbf[grow + NHALF + feat] = f2bf(yb); }
            if (lastl)  { xout[grow + feat] = yb;         xfbf[grow + feat] = f2bf(yb); }
          }
        }
      }
  }

  // jac: sum over 16 c-lanes (odd lanes contribute 0), plain store (row owned)
#pragma unroll
  for (int i = 0; i < 2; i++)
#pragma unroll
    for (int r = 0; r < 4; r++) {
      float v = jr[i][r];
      v += __shfl_xor(v, 1); v += __shfl_xor(v, 2);
      v += __shfl_xor(v, 4); v += __shfl_xor(v, 8);
      if (c == 0) jac[m0 + 16 * i + 4 * q + r] = v;
    }
}

// ---------------------------------------------------------------- VQ argmax
static __device__ __forceinline__ void vq_stage(const unsigned short* __restrict__ P,
                                                int n0, int wave, int lane,
                                                unsigned short* dst) {
#pragma unroll
  for (int u = 0; u < 8; u++) {
    const int chb = (wave * 8 + u) * 64;
    const int ch = chb + lane;
    const int kseg = ch >> 9, cs = ch & 511;
    const int row = cs >> 3, cc = (cs & 7) ^ (row & 7);
    load_lds16(P + (size_t)(n0 + row) * 256 + kseg * 64 + cc * 8, dst + chb * 8);
  }
}

// Grid 512: slice = bx & 15 (XCD-pinned, 2 MB P slice per XCD -> L2-resident),
// m-group = bx >> 4 (256 rows). 64 register-resident X rows per wave.
// DOUBLE-BUFFERED P tiles: 1 barrier/tile; stage nt+1 issued right after the
// barrier so its latency hides under tile nt's compute.
__global__ __launch_bounds__(256, 2)
void vq_argmax(const unsigned short* __restrict__ X,    // [NB][256] bf16
               const unsigned short* __restrict__ P,    // [NK][256] bf16
               const float* __restrict__ nbh,           // [NK] = 0.5*||p||^2
               unsigned long long* __restrict__ gbest)  // [NB] packed
{
  __shared__ __align__(16) unsigned short Bs[2][16384];  // 2 x 32 KB
  const int tid = threadIdx.x;
  const int lane = tid & 63, wave = tid >> 6;
  const int y = blockIdx.x & 15;
  const int m0 = (blockIdx.x >> 4) * 256;
  const int q = lane >> 4, c = lane & 15;
  const int mw = m0 + wave * 64;
  const int nbase = y * 2048;

  bf16x8 af[4][8];
#pragma unroll
  for (int i = 0; i < 4; i++) {
    const unsigned short* xr = X + (size_t)(mw + 16 * i + c) * 256 + q * 8;
#pragma unroll
    for (int kc = 0; kc < 8; kc++) af[i][kc] = *(const bf16x8*)(xr + kc * 32);
  }

  float bestv[16];
  int besti[16];
#pragma unroll
  for (int t = 0; t < 16; t++) { bestv[t] = -1e30f; besti[t] = 0; }

  vq_stage(P, nbase, wave, lane, Bs[0]);

  for (int nt = 0; nt < 32; nt++) {
    __syncthreads();                          // buf[nt&1] ready, other half free
    if (nt < 31) vq_stage(P, nbase + (nt + 1) * 64, wave, lane, Bs[(nt + 1) & 1]);
    const unsigned short* B = Bs[nt & 1];
    const int n0 = nbase + nt * 64;

    float nb4[4];
#pragma unroll
    for (int j = 0; j < 4; j++) nb4[j] = nbh[n0 + 16 * j + c];

    const f32x4 z = {0.f, 0.f, 0.f, 0.f};
    f32x4 acc[4][4];
#pragma unroll
    for (int i = 0; i < 4; i++)
#pragma unroll
      for (int j = 0; j < 4; j++) acc[i][j] = z;

#pragma unroll
    for (int kseg = 0; kseg < 4; kseg++)
#pragma unroll
      for (int ks = 0; ks < 2; ks++) {
        const int kc = kseg * 2 + ks;
        const int g = ks * 4 + q;
#pragma unroll
        for (int j = 0; j < 4; j++) {
          const int rb = 16 * j + c;
          const bf16x8 bf = *(const bf16x8*)(B + (kseg * 64 + rb) * 64 + ((g ^ (rb & 7)) * 8));
          acc[0][j] = __builtin_amdgcn_mfma_f32_16x16x32_bf16(af[0][kc], bf, acc[0][j], 0, 0, 0);
          acc[1][j] = __builtin_amdgcn_mfma_f32_16x16x32_bf16(af[1][kc], bf, acc[1][j], 0, 0, 0);
          acc[2][j] = __builtin_amdgcn_mfma_f32_16x16x32_bf16(af[2][kc], bf, acc[2][j], 0, 0, 0);
          acc[3][j] = __builtin_amdgcn_mfma_f32_16x16x32_bf16(af[3][kc], bf, acc[3][j], 0, 0, 0);
        }
      }

    // lane-local running argmax (ascending col + strict > = lowest-index ties)
#pragma unroll
    for (int j = 0; j < 4; j++) {
      const int col = n0 + 16 * j + c;
      const float nb = nb4[j];
#pragma unroll
      for (int i = 0; i < 4; i++)
#pragma unroll
        for (int r = 0; r < 4; r++) {
          const float sc = acc[i][j][r] - nb;
          const int t = i * 4 + r;
          if (sc > bestv[t]) { bestv[t] = sc; besti[t] = col; }
        }
    }
  }

  // reduce across 16 c-lanes per slot; rows unique per (wave, i, q, r)
#pragma unroll
  for (int t = 0; t < 16; t++) {
    float lv = bestv[t]; int li = besti[t];
#pragma unroll
    for (int mk = 8; mk >= 1; mk >>= 1) {
      const float ov = __shfl_xor(lv, mk);
      const int oi = __shfl_xor(li, mk);
      if (ov > lv || (ov == lv && oi < li)) { lv = ov; li = oi; }
    }
    if (c == 0) {
      const int row = mw + 16 * (t >> 2) + q * 4 + (t & 3);
      atomicMax(&gbest[row], packsi(lv, li));
    }
  }
}

// ---------------------------------------------------------------- fused prep
// bx [0,2048): prior cast+norm (16 codes/block, coalesced)
// bx [2048,2112): W1 transpose via LDS 64x64 tiles (coalesced both sides)
// bx [2112,2240): Ws/Wt -> W2I interleaved transpose
// bx [2240,2272): gbest/accum init
__global__ void prep_all(const float* __restrict__ W1,
                         const float* __restrict__ Ws,
                         const float* __restrict__ Wt,
                         const float* __restrict__ prior,
                         unsigned short* __restrict__ W1T,
                         unsigned short* __restrict__ W2I,
                         unsigned short* __restrict__ pbf,
                         float* __restrict__ nbh,
                         unsigned long long* __restrict__ gbest,
                         float* __restrict__ accum)
{
  __shared__ float ts[64 * 65];
  const int bx = blockIdx.x;
  const int tid = threadIdx.x;
  if (bx < 2048) {
    const int k = bx * 16 + (tid >> 4);      // code index
    const int l16 = tid & 15;
    float s = 0.f;
#pragma unroll
    for (int v = 0; v < 4; v++) {
      const int off = (v * 16 + l16) * 4;
      const float4 d = *(const float4*)(prior + (size_t)k * NF + off);
      ushort4 o;
      o.x = f2bf(d.x); o.y = f2bf(d.y); o.z = f2bf(d.z); o.w = f2bf(d.w);
      *(ushort4*)(pbf + (size_t)k * NF + off) = o;
      s += d.x * d.x + d.y * d.y + d.z * d.z + d.w * d.w;
    }
#pragma unroll
    for (int mk = 8; mk >= 1; mk >>= 1) s += __shfl_xor(s, mk);
    if (l16 == 0) nbh[k] = 0.5f * s;
  } else if (bx < 2112) {
    const int job = bx - 2048;
    const int l = job >> 4, t = job & 15;
    const int k0 = (t >> 3) * 64, n0 = (t & 7) * 64;
    const float* src = W1 + (size_t)l * NHALF * NHID;
#pragma unroll
    for (int v = 0; v < 16; v++) {
      const int e = tid + v * 256;
      const int kk = e >> 6, nn = e & 63;
      ts[kk * 65 + nn] = src[(size_t)(k0 + kk) * NHID + n0 + nn];
    }
    __syncthreads();
    unsigned short* dst = W1T + (size_t)l * NHID * NHALF;
#pragma unroll
    for (int v = 0; v < 16; v++) {
      const int e = tid + v * 256;
      const int nn = e >> 6, kk = e & 63;
      dst[(size_t)(n0 + nn) * NHALF + k0 + kk] = f2bf(ts[kk * 65 + nn]);
    }
  } else if (bx < 2240) {
    const int job = bx - 2112;
    const int l = job >> 5, rem = job & 31;
    const int b = rem >> 4;
    const int k0 = ((rem >> 1) & 7) * 64;
    const int f0 = (rem & 1) * 64;
    const float* src = (b ? Wt : Ws) + (size_t)l * NHID * NHALF;
#pragma unroll
    for (int v = 0; v < 16; v++) {
      const int e = tid + v * 256;
      const int kk = e >> 6, nn = e & 63;
      ts[kk * 65 + nn] = src[(size_t)(k0 + kk) * NHALF + f0 + nn];
    }
    __syncthreads();
#pragma unroll
    for (int v = 0; v < 16; v++) {
      const int e = tid + v * 256;
      const int nn = e >> 6, kk = e & 63;
      W2I[((size_t)l * NF + 2 * (f0 + nn) + b) * NHID + k0 + kk] = f2bf(ts[kk * 65 + nn]);
    }
  } else {
    const int idx = (bx - 2240) * 256 + tid;
    if (idx < NB) gbest[idx] = 0ull;
    if (idx < 2) accum[idx] = 0.f;
  }
}

// ---------------------------------------------------------------- VQ finalize
__global__ void vq_finalize(const float* __restrict__ X,      // d_out x, fp32
                            const float* __restrict__ prior,
                            const unsigned long long* __restrict__ gbest,
                            const float* __restrict__ jac,
                            float* __restrict__ accum)        // [0]=dist,[1]=jac
{
  const int wave = threadIdx.x >> 6, lane = threadIdx.x & 63;
  const int gw = blockIdx.x * 4 + wave;        // 1024 waves, 8 rows each
  float accd = 0.f, accj = 0.f;
  for (int r = 0; r < 8; r++) {
    const int row = gw * 8 + r;
    const unsigned int idx = ~(unsigned int)(gbest[row]);   // low 32 bits = ~idx
    const float* x = X + (size_t)row * NF;
    const float* p = prior + (size_t)idx * NF;
#pragma unroll
    for (int u = 0; u < 4; u++) {
      const int d = lane + u * 64;
      const float df = x[d] - p[d];
      accd += df * df;
    }
    if (lane == 0) accj += jac[row];
  }
#pragma unroll
  for (int mk = 32; mk >= 1; mk >>= 1) {
    accd += __shfl_xor(accd, mk);
    accj += __shfl_xor(accj, mk);
  }
  __shared__ float sd[4], sj[4];
  if (lane == 0) { sd[wave] = accd; sj[wave] = accj; }
  __syncthreads();
  if (threadIdx.x == 0) {
    atomicAdd(&accum[0], sd[0] + sd[1] + sd[2] + sd[3]);
    atomicAdd(&accum[1], sj[0] + sj[1] + sj[2] + sj[3]);
  }
}

__global__ void finalize_loss(const float* __restrict__ acc, float* __restrict__ loss) {
  if (threadIdx.x == 0 && blockIdx.x == 0)
    loss[0] = 1.25f * (0.5f * acc[0] / (float)NB) - acc[1] / (float)NB;
}

// ---------------------------------------------------------------- launch
extern "C" void kernel_launch(void* const* d_in, const int* in_sizes, int n_in,
                              void* d_out, int out_size, void* d_ws, size_t ws_size,
                              hipStream_t stream)
{
  (void)in_sizes; (void)n_in; (void)out_size; (void)ws_size;
  const float* inputs = (const float*)d_in[0];
  const float* W1 = (const float*)d_in[1];
  const float* b1 = (const float*)d_in[2];
  const float* Ws = (const float*)d_in[3];
  const float* bs = (const float*)d_in[4];
  const float* Wt = (const float*)d_in[5];
  const float* bt = (const float*)d_in[6];
  const float* prior = (const float*)d_in[7];

  char* p = (char*)d_ws;
  auto alloc = [&](size_t bytes) { char* r = p; p += (bytes + 255) & ~(size_t)255; return r; };
  unsigned short* W1T  = (unsigned short*)alloc((size_t)NLAY * NHID * NHALF * 2);
  unsigned short* W2I  = (unsigned short*)alloc((size_t)NLAY * NF * NHID * 2);
  unsigned short* PBF  = (unsigned short*)alloc((size_t)NK * NF * 2);
  float* NBH           = (float*)alloc((size_t)NK * 4);
  unsigned short* XFBF = (unsigned short*)alloc((size_t)NB * NF * 2);
  float* JAC           = (float*)alloc((size_t)NB * 4);
  unsigned long long* GBEST = (unsigned long long*)alloc((size_t)NB * 8);
  float* ACC           = (float*)alloc(256);

  float* xout = (float*)d_out;                 // [NB][NF]
  float* loss = xout + (size_t)NB * NF;        // scalar

  prep_all<<<dim3(2272), 256, 0, stream>>>(
      W1, Ws, Wt, prior, W1T, W2I, PBF, NBH, GBEST, ACC);

  flow_all<<<dim3(NB / 32), 256, 0, stream>>>(
      inputs, W1T, W2I, b1, bs, bt, xout, XFBF, JAC);

  vq_argmax<<<dim3(32 * 16), 256, 0, stream>>>(XFBF, PBF, NBH, GBEST);
  vq_finalize<<<dim3(256), 256, 0, stream>>>(xout, prior, GBEST, JAC, ACC);
  finalize_loss<<<1, 1, 0, stream>>>(ACC, loss);
}

// Round 6
// 293.636 us; speedup vs baseline: 1.2081x; 1.2081x over previous
//
#include <hip/hip_runtime.h>
#include <stdint.h>

// ---------------------------------------------------------------- constants
#define NB     8192     // batch
#define NF     256      // features
#define NHALF  128      // F/2
#define NHID   512      // hidden = 2F
#define NLAY   4        // coupling layers
#define NK     32768    // codebook size

typedef __attribute__((ext_vector_type(8))) short bf16x8;   // 8 bf16 = 4 VGPR
typedef __attribute__((ext_vector_type(4))) float f32x4;

static __device__ __forceinline__ unsigned short f2bf(float f) {
  union { float f; unsigned int u; } v; v.f = f;
  return (unsigned short)((v.u + 0x7FFFu + ((v.u >> 16) & 1u)) >> 16);  // RNE
}
static __device__ __forceinline__ float bf2f(unsigned short u) {
  union { unsigned int u; float f; } v; v.u = ((unsigned int)u) << 16; return v.f;
}

// async global->LDS, 16B per lane; LDS dest = wave-uniform base + lane*16
static __device__ __forceinline__ void load_lds16(const void* g, void* l) {
  __builtin_amdgcn_global_load_lds(
      (const __attribute__((address_space(1))) unsigned int*)g,
      (__attribute__((address_space(3))) unsigned int*)l, 16, 0, 0);
}

// pack (score, idx) so u64 max == argmax with smallest-index tiebreak
static __device__ __forceinline__ unsigned long long packsi(float v, int idx) {
  unsigned int b = __float_as_uint(v);
  b = (b & 0x80000000u) ? ~b : (b | 0x80000000u);   // order-preserving map
  return ((unsigned long long)b << 32) | (unsigned int)(~(unsigned int)idx);
}

static __device__ __forceinline__ float fast_tanh(float x) {
  const float xc = fminf(fmaxf(x, -15.f), 15.f);
  const float e2 = __expf(2.f * xc);
  return 1.f - 2.f / (e2 + 1.f);
}

// LDS tile address: [kseg][row][64 shorts], 3-bit XOR chunk swizzle.
// Proven 0-conflict (R2/R4 evidence) for ds_read_b128 with 16 lanes on rows.
static __device__ __forceinline__ int swadr(int kseg, int nrows, int row, int kin) {
  return (kseg * nrows + row) * 64 + (((kin >> 3) ^ (row & 7)) * 8) + (kin & 7);
}

// ---------------------------------------------------------------- fused flow (ALL 4 layers)
// One block = 16 batch rows, grid 512 -> 2 blocks/CU co-resident (LDS 40 KB)
// so barrier waits of one block hide under the other block's compute (m114).
// Coupling recurrence is row-local: xb_{l+1}=xa_l, xa_{l+1}=yb_l -> two bf16
// LDS buffers ping-pong, yb overwrites xb in place (same owner thread).
// jac: per-wave register partials -> LDS cross-wave reduce (NO plain-store
// race as in R5, no atomics/init needed).
__global__ __launch_bounds__(256, 2)
void flow_all(const float* __restrict__ in,
              const unsigned short* __restrict__ W1T,   // [L][512][128]
              const unsigned short* __restrict__ W2I,   // [L][256][512] s/t interleaved
              const float* __restrict__ b1A,
              const float* __restrict__ bsA,
              const float* __restrict__ btA,
              float* __restrict__ xout,
              unsigned short* __restrict__ xfbf,
              float* __restrict__ jac)
{
  __shared__ __align__(16) unsigned short Xb[2][16 * 128];   //  8 KB x-state
  __shared__ __align__(16) unsigned short Hs[2 * 16 * 64];   //  4 KB h chunk
  __shared__ __align__(16) unsigned short Bs[2048 * 8];      // 32 KB W staging
  __shared__ float jlds[3][16];
  const int tid = threadIdx.x;
  const int lane = tid & 63, wave = tid >> 6;
  const int q = lane >> 4, c = lane & 15;
  const int m0 = blockIdx.x * 16;

  // ---- init: Xb[0] = bf16(in[:, :128]) (xa_0), Xb[1] = bf16(in[:, 128:]) (xb_0)
#pragma unroll
  for (int v = 0; v < 4; v++) {
    const int t4 = tid + v * 256;            // 1024 float4s = 16 rows x 64
    const int row = t4 >> 6, f4 = t4 & 63;
    const float4 d = *(const float4*)(in + (size_t)(m0 + row) * NF + f4 * 4);
    unsigned short* dst = Xb[f4 >> 5];
    const int feat = (f4 & 31) * 4;
    const float vals[4] = {d.x, d.y, d.z, d.w};
#pragma unroll
    for (int u = 0; u < 4; u++) {
      const int fe = feat + u;
      dst[swadr(fe >> 6, 16, row, fe & 63)] = f2bf(vals[u]);
    }
  }

  float jr[4];
#pragma unroll
  for (int r = 0; r < 4; r++) jr[r] = 0.f;

  for (int l = 0; l < NLAY; l++) {
    __syncthreads();                          // x-state writes visible
    const unsigned short* W1l = W1T + (size_t)l * NHID * NHALF;
    const unsigned short* W2l = W2I + (size_t)l * NF * NHID;
    const float* b1l = b1A + l * NHID;
    const float* bsl = bsA + l * NHALF;
    const float* btl = btA + l * NHALF;
    unsigned short* XA = Xb[l & 1];
    unsigned short* XB = Xb[1 - (l & 1)];

    // GEMM1 A-fragments from XA (LDS): row = c, k-chunk = kw*4+q
    bf16x8 af1[4];
#pragma unroll
    for (int kw = 0; kw < 4; kw++) {
      const int kch = kw * 4 + q;
      af1[kw] = *(const bf16x8*)(XA + ((kch >> 3) * 16 + c) * 64 +
                                 (((kch & 7) ^ (c & 7)) * 8));
    }

    const f32x4 z = {0.f, 0.f, 0.f, 0.f};
    f32x4 acc2[4];
#pragma unroll
    for (int j = 0; j < 4; j++) acc2[j] = z;

    for (int nc = 0; nc < 4; nc++) {
      __syncthreads();                        // Bs free
      // stage W1T[nc*128 .. +128][0..128] as [kseg2][128][64]
#pragma unroll
      for (int u = 0; u < 8; u++) {
        const int chb = (wave * 8 + u) * 64;
        const int ch = chb + lane;
        const int kseg = ch >> 10, cs = ch & 1023;
        const int row = cs >> 3, cc = (cs & 7) ^ (row & 7);
        load_lds16(W1l + (size_t)(nc * 128 + row) * NHALF + kseg * 64 + cc * 8,
                   Bs + chb * 8);
      }
      __syncthreads();

      f32x4 acc1[2];
#pragma unroll
      for (int j = 0; j < 2; j++) acc1[j] = z;

#pragma unroll
      for (int kw = 0; kw < 4; kw++) {
        const int kseg = kw >> 1, g = (kw & 1) * 4 + q;
#pragma unroll
        for (int j = 0; j < 2; j++) {
          const int rb = wave * 32 + 16 * j + c;
          const bf16x8 bf = *(const bf16x8*)(Bs + (kseg * 128 + rb) * 64 + ((g ^ (rb & 7)) * 8));
          acc1[j] = __builtin_amdgcn_mfma_f32_16x16x32_bf16(af1[kw], bf, acc1[j], 0, 0, 0);
        }
      }
      // h chunk -> Hs [kseg2][16][64] (relu + bias)
#pragma unroll
      for (int j = 0; j < 2; j++) {
        const int hc = wave * 32 + 16 * j + c;      // 0..127 within chunk
        const float bb = b1l[nc * 128 + hc];
#pragma unroll
        for (int r = 0; r < 4; r++) {
          float v = acc1[j][r] + bb;
          v = v > 0.f ? v : 0.f;
          Hs[swadr(hc >> 6, 16, 4 * q + r, hc & 63)] = f2bf(v);
        }
      }

      for (int kt2 = 0; kt2 < 2; kt2++) {
        __syncthreads();                      // Hs ready / Bs free
        // stage W2I[0..256][nc*128 + kt2*64 .. +64] as [256][64]
#pragma unroll
        for (int u = 0; u < 8; u++) {
          const int chb = (wave * 8 + u) * 64;
          const int ch = chb + lane;
          const int row = ch >> 3, cc = (ch & 7) ^ (row & 7);
          load_lds16(W2l + (size_t)row * NHID + nc * 128 + kt2 * 64 + cc * 8,
                     Bs + chb * 8);
        }
        __syncthreads();
#pragma unroll
        for (int ks = 0; ks < 2; ks++) {
          const int g = ks * 4 + q;
          const bf16x8 afh = *(const bf16x8*)(Hs + (kt2 * 16 + c) * 64 + ((g ^ (c & 7)) * 8));
#pragma unroll
          for (int j = 0; j < 4; j++) {
            const int rb = wave * 64 + 16 * j + c;
            const bf16x8 bf = *(const bf16x8*)(Bs + rb * 64 + ((g ^ (rb & 7)) * 8));
            acc2[j] = __builtin_amdgcn_mfma_f32_16x16x32_bf16(afh, bf, acc2[j], 0, 0, 0);
          }
        }
      }
    }

    // ---- coupling epilogue (even col=s, odd col=t)
    const int parity = c & 1;
    const int lastl = (l == NLAY - 1);
#pragma unroll
    for (int j = 0; j < 4; j++) {
      const int col = wave * 64 + 16 * j + c;
#pragma unroll
      for (int r = 0; r < 4; r++) {
        const float val = acc2[j][r];
        const float oth = __shfl_xor(val, 1);     // all lanes participate
        if (!parity) {
          const int feat = col >> 1;
          float s = val + bsl[feat];
          if (!lastl) s = fast_tanh(s);
          const float t = oth + btl[feat];
          const int row = 4 * q + r;
          const int xaddr = swadr(feat >> 6, 16, row, feat & 63);
          const float xb = bf2f(XB[xaddr]);
          const float yb = xb * __expf(s) + t;
          jr[r] += s;
          XB[xaddr] = f2bf(yb);                   // in-place: same owner thread
          const size_t grow = (size_t)(m0 + row) * NF;
          if (l == 2) { xout[grow + NHALF + feat] = yb; xfbf[grow + NHALF + feat] = f2bf(yb); }
          if (lastl)  { xout[grow + feat] = yb;         xfbf[grow + feat] = f2bf(yb); }
        }
      }
    }
  }

  // jac: reduce 16 c-lanes in-wave, then cross-wave via LDS (waves split cols
  // of the SAME rows -> must sum, not overwrite; R5 had a race here)
  float v0[4];
#pragma unroll
  for (int r = 0; r < 4; r++) {
    float v = jr[r];
    v += __shfl_xor(v, 1); v += __shfl_xor(v, 2);
    v += __shfl_xor(v, 4); v += __shfl_xor(v, 8);
    if (c == 0) {
      if (wave) jlds[wave - 1][4 * q + r] = v;
      else v0[r] = v;
    }
  }
  __syncthreads();
  if (wave == 0 && c == 0) {
#pragma unroll
    for (int r = 0; r < 4; r++) {
      const int row = 4 * q + r;
      jac[m0 + row] = v0[r] + jlds[0][row] + jlds[1][row] + jlds[2][row];
    }
  }
}

// ---------------------------------------------------------------- VQ argmax
// (exact R4 structure: 2 barriers/tile, single 32 KB buffer — the R5
// double-buffer variant REGRESSED 136->189 µs from LDS port contention
// between the prefetch DMA-writes and the MFMA-feeding ds_reads)
// Grid 512: slice = bx & 15 (XCD-pinned, 2 MB P slice per XCD -> L2-resident),
// m-group = bx >> 4 (256 rows). 64 register-resident X rows per wave.
__global__ __launch_bounds__(256, 2)
void vq_argmax(const unsigned short* __restrict__ X,    // [NB][256] bf16
               const unsigned short* __restrict__ P,    // [NK][256] bf16
               const float* __restrict__ nbh,           // [NK] = 0.5*||p||^2
               unsigned long long* __restrict__ gbest)  // [NB] packed
{
  __shared__ __align__(16) unsigned short Bs[4 * 64 * 64];   // 32 KB
  const int tid = threadIdx.x;
  const int lane = tid & 63, wave = tid >> 6;
  const int y = blockIdx.x & 15;
  const int m0 = (blockIdx.x >> 4) * 256;
  const int q = lane >> 4, c = lane & 15;
  const int mw = m0 + wave * 64;

  bf16x8 af[4][8];
#pragma unroll
  for (int i = 0; i < 4; i++) {
    const unsigned short* xr = X + (size_t)(mw + 16 * i + c) * 256 + q * 8;
#pragma unroll
    for (int kc = 0; kc < 8; kc++) af[i][kc] = *(const bf16x8*)(xr + kc * 32);
  }

  float bestv[16];
  int besti[16];
#pragma unroll
  for (int t = 0; t < 16; t++) { bestv[t] = -1e30f; besti[t] = 0; }

  for (int nt = 0; nt < 32; nt++) {
    const int n0 = y * 2048 + nt * 64;
    if (nt) __syncthreads();
    // stage 64 codes x 256 k as [kseg4][64][64]
#pragma unroll
    for (int u = 0; u < 8; u++) {
      const int chb = (wave * 8 + u) * 64;
      const int ch = chb + lane;
      const int kseg = ch >> 9, cs = ch & 511;
      const int row = cs >> 3, cc = (cs & 7) ^ (row & 7);
      load_lds16(P + (size_t)(n0 + row) * 256 + kseg * 64 + cc * 8, Bs + chb * 8);
    }
    __syncthreads();

    const f32x4 z = {0.f, 0.f, 0.f, 0.f};
    f32x4 acc[4][4];
#pragma unroll
    for (int i = 0; i < 4; i++)
#pragma unroll
      for (int j = 0; j < 4; j++) acc[i][j] = z;

#pragma unroll
    for (int kseg = 0; kseg < 4; kseg++)
#pragma unroll
      for (int ks = 0; ks < 2; ks++) {
        const int kc = kseg * 2 + ks;
        const int g = ks * 4 + q;
#pragma unroll
        for (int j = 0; j < 4; j++) {
          const int rb = 16 * j + c;
          const bf16x8 bf = *(const bf16x8*)(Bs + (kseg * 64 + rb) * 64 + ((g ^ (rb & 7)) * 8));
          acc[0][j] = __builtin_amdgcn_mfma_f32_16x16x32_bf16(af[0][kc], bf, acc[0][j], 0, 0, 0);
          acc[1][j] = __builtin_amdgcn_mfma_f32_16x16x32_bf16(af[1][kc], bf, acc[1][j], 0, 0, 0);
          acc[2][j] = __builtin_amdgcn_mfma_f32_16x16x32_bf16(af[2][kc], bf, acc[2][j], 0, 0, 0);
          acc[3][j] = __builtin_amdgcn_mfma_f32_16x16x32_bf16(af[3][kc], bf, acc[3][j], 0, 0, 0);
        }
      }

    // lane-local running argmax (ascending col + strict > = lowest-index ties)
#pragma unroll
    for (int j = 0; j < 4; j++) {
      const int col = n0 + 16 * j + c;
      const float nb = nbh[col];
#pragma unroll
      for (int i = 0; i < 4; i++)
#pragma unroll
        for (int r = 0; r < 4; r++) {
          const float sc = acc[i][j][r] - nb;
          const int t = i * 4 + r;
          if (sc > bestv[t]) { bestv[t] = sc; besti[t] = col; }
        }
    }
  }

  // reduce across 16 c-lanes per slot; rows unique per (wave, i, q, r)
#pragma unroll
  for (int t = 0; t < 16; t++) {
    float lv = bestv[t]; int li = besti[t];
#pragma unroll
    for (int mk = 8; mk >= 1; mk >>= 1) {
      const float ov = __shfl_xor(lv, mk);
      const int oi = __shfl_xor(li, mk);
      if (ov > lv || (ov == lv && oi < li)) { lv = ov; li = oi; }
    }
    if (c == 0) {
      const int row = mw + 16 * (t >> 2) + q * 4 + (t & 3);
      atomicMax(&gbest[row], packsi(lv, li));
    }
  }
}

// ---------------------------------------------------------------- fused prep
// bx [0,2048): prior cast+norm | [2048,2112): W1 transpose | [2112,2240):
// Ws/Wt -> W2I interleaved transpose | [2240,2272): gbest/accum init
__global__ void prep_all(const float* __restrict__ W1,
                         const float* __restrict__ Ws,
                         const float* __restrict__ Wt,
                         const float* __restrict__ prior,
                         unsigned short* __restrict__ W1T,
                         unsigned short* __restrict__ W2I,
                         unsigned short* __restrict__ pbf,
                         float* __restrict__ nbh,
                         unsigned long long* __restrict__ gbest,
                         float* __restrict__ accum)
{
  __shared__ float ts[64 * 65];
  const int bx = blockIdx.x;
  const int tid = threadIdx.x;
  if (bx < 2048) {
    const int k = bx * 16 + (tid >> 4);      // code index
    const int l16 = tid & 15;
    float s = 0.f;
#pragma unroll
    for (int v = 0; v < 4; v++) {
      const int off = (v * 16 + l16) * 4;
      const float4 d = *(const float4*)(prior + (size_t)k * NF + off);
      ushort4 o;
      o.x = f2bf(d.x); o.y = f2bf(d.y); o.z = f2bf(d.z); o.w = f2bf(d.w);
      *(ushort4*)(pbf + (size_t)k * NF + off) = o;
      s += d.x * d.x + d.y * d.y + d.z * d.z + d.w * d.w;
    }
#pragma unroll
    for (int mk = 8; mk >= 1; mk >>= 1) s += __shfl_xor(s, mk);
    if (l16 == 0) nbh[k] = 0.5f * s;
  } else if (bx < 2112) {
    const int job = bx - 2048;
    const int l = job >> 4, t = job & 15;
    const int k0 = (t >> 3) * 64, n0 = (t & 7) * 64;
    const float* src = W1 + (size_t)l * NHALF * NHID;
#pragma unroll
    for (int v = 0; v < 16; v++) {
      const int e = tid + v * 256;
      const int kk = e >> 6, nn = e & 63;
      ts[kk * 65 + nn] = src[(size_t)(k0 + kk) * NHID + n0 + nn];
    }
    __syncthreads();
    unsigned short* dst = W1T + (size_t)l * NHID * NHALF;
#pragma unroll
    for (int v = 0; v < 16; v++) {
      const int e = tid + v * 256;
      const int nn = e >> 6, kk = e & 63;
      dst[(size_t)(n0 + nn) * NHALF + k0 + kk] = f2bf(ts[kk * 65 + nn]);
    }
  } else if (bx < 2240) {
    const int job = bx - 2112;
    const int l = job >> 5, rem = job & 31;
    const int b = rem >> 4;
    const int k0 = ((rem >> 1) & 7) * 64;
    const int f0 = (rem & 1) * 64;
    const float* src = (b ? Wt : Ws) + (size_t)l * NHID * NHALF;
#pragma unroll
    for (int v = 0; v < 16; v++) {
      const int e = tid + v * 256;
      const int kk = e >> 6, nn = e & 63;
      ts[kk * 65 + nn] = src[(size_t)(k0 + kk) * NHALF + f0 + nn];
    }
    __syncthreads();
#pragma unroll
    for (int v = 0; v < 16; v++) {
      const int e = tid + v * 256;
      const int nn = e >> 6, kk = e & 63;
      W2I[((size_t)l * NF + 2 * (f0 + nn) + b) * NHID + k0 + kk] = f2bf(ts[kk * 65 + nn]);
    }
  } else {
    const int idx = (bx - 2240) * 256 + tid;
    if (idx < NB) gbest[idx] = 0ull;
    if (idx < 2) accum[idx] = 0.f;
  }
}

// ---------------------------------------------------------------- VQ finalize
__global__ void vq_finalize(const float* __restrict__ X,      // d_out x, fp32
                            const float* __restrict__ prior,
                            const unsigned long long* __restrict__ gbest,
                            const float* __restrict__ jac,
                            float* __restrict__ accum)        // [0]=dist,[1]=jac
{
  const int wave = threadIdx.x >> 6, lane = threadIdx.x & 63;
  const int gw = blockIdx.x * 4 + wave;        // 1024 waves, 8 rows each
  float accd = 0.f, accj = 0.f;
  for (int r = 0; r < 8; r++) {
    const int row = gw * 8 + r;
    const unsigned int idx = ~(unsigned int)(gbest[row]);   // low 32 bits = ~idx
    const float* x = X + (size_t)row * NF;
    const float* p = prior + (size_t)idx * NF;
#pragma unroll
    for (int u = 0; u < 4; u++) {
      const int d = lane + u * 64;
      const float df = x[d] - p[d];
      accd += df * df;
    }
    if (lane == 0) accj += jac[row];
  }
#pragma unroll
  for (int mk = 32; mk >= 1; mk >>= 1) {
    accd += __shfl_xor(accd, mk);
    accj += __shfl_xor(accj, mk);
  }
  __shared__ float sd[4], sj[4];
  if (lane == 0) { sd[wave] = accd; sj[wave] = accj; }
  __syncthreads();
  if (threadIdx.x == 0) {
    atomicAdd(&accum[0], sd[0] + sd[1] + sd[2] + sd[3]);
    atomicAdd(&accum[1], sj[0] + sj[1] + sj[2] + sj[3]);
  }
}

__global__ void finalize_loss(const float* __restrict__ acc, float* __restrict__ loss) {
  if (threadIdx.x == 0 && blockIdx.x == 0)
    loss[0] = 1.25f * (0.5f * acc[0] / (float)NB) - acc[1] / (float)NB;
}

// ---------------------------------------------------------------- launch
extern "C" void kernel_launch(void* const* d_in, const int* in_sizes, int n_in,
                              void* d_out, int out_size, void* d_ws, size_t ws_size,
                              hipStream_t stream)
{
  (void)in_sizes; (void)n_in; (void)out_size; (void)ws_size;
  const float* inputs = (const float*)d_in[0];
  const float* W1 = (const float*)d_in[1];
  const float* b1 = (const float*)d_in[2];
  const float* Ws = (const float*)d_in[3];
  const float* bs = (const float*)d_in[4];
  const float* Wt = (const float*)d_in[5];
  const float* bt = (const float*)d_in[6];
  const float* prior = (const float*)d_in[7];

  char* p = (char*)d_ws;
  auto alloc = [&](size_t bytes) { char* r = p; p += (bytes + 255) & ~(size_t)255; return r; };
  unsigned short* W1T  = (unsigned short*)alloc((size_t)NLAY * NHID * NHALF * 2);
  unsigned short* W2I  = (unsigned short*)alloc((size_t)NLAY * NF * NHID * 2);
  unsigned short* PBF  = (unsigned short*)alloc((size_t)NK * NF * 2);
  float* NBH           = (float*)alloc((size_t)NK * 4);
  unsigned short* XFBF = (unsigned short*)alloc((size_t)NB * NF * 2);
  float* JAC           = (float*)alloc((size_t)NB * 4);
  unsigned long long* GBEST = (unsigned long long*)alloc((size_t)NB * 8);
  float* ACC           = (float*)alloc(256);

  float* xout = (float*)d_out;                 // [NB][NF]
  float* loss = xout + (size_t)NB * NF;        // scalar

  prep_all<<<dim3(2272), 256, 0, stream>>>(
      W1, Ws, Wt, prior, W1T, W2I, PBF, NBH, GBEST, ACC);

  flow_all<<<dim3(NB / 16), 256, 0, stream>>>(
      inputs, W1T, W2I, b1, bs, bt, xout, XFBF, JAC);

  vq_argmax<<<dim3(32 * 16), 256, 0, stream>>>(XFBF, PBF, NBH, GBEST);
  vq_finalize<<<dim3(256), 256, 0, stream>>>(xout, prior, GBEST, JAC, ACC);
  finalize_loss<<<1, 1, 0, stream>>>(ACC, loss);
}

// Round 7
// 291.751 us; speedup vs baseline: 1.2159x; 1.0065x over previous
//
#include <hip/hip_runtime.h>
#include <hip/hip_fp8.h>
#include <stdint.h>

// ---------------------------------------------------------------- constants
#define NB     8192     // batch
#define NF     256      // features
#define NHALF  128      // F/2
#define NHID   512      // hidden = 2F
#define NLAY   4        // coupling layers
#define NK     32768    // codebook size

#define SX     (1.0f / 16.0f)    // x scale for fp8 (|x|<=474/16=30 < 448)
#define SP     (256.0f)          // p scale for fp8 (Glorot +-0.0135*256=3.46)

typedef __attribute__((ext_vector_type(8))) short bf16x8;   // 8 bf16 = 4 VGPR
typedef __attribute__((ext_vector_type(4))) float f32x4;
typedef __attribute__((ext_vector_type(2))) long i64x2;     // 16 B = 2 fp8 frags

static __device__ __forceinline__ unsigned short f2bf(float f) {
  union { float f; unsigned int u; } v; v.f = f;
  return (unsigned short)((v.u + 0x7FFFu + ((v.u >> 16) & 1u)) >> 16);  // RNE
}
static __device__ __forceinline__ float bf2f(unsigned short u) {
  union { unsigned int u; float f; } v; v.u = ((unsigned int)u) << 16; return v.f;
}
static __device__ __forceinline__ unsigned char f2fp8(float f) {
  __hip_fp8_e4m3 q(f);                       // OCP e4m3fn, RNE + saturate
  return (unsigned char)q.__x;
}
static __device__ __forceinline__ float fp82f(unsigned char b) {
  __hip_fp8_e4m3 q; q.__x = b; return (float)q;
}
// permuted byte index inside a 256-k row: k' = q*64 + kc*8 + j for
// k = kc*32 + q*8 + j  -> one 16B load at q*64+kc2*16 = two K=32 fp8 frags
static __device__ __forceinline__ int kperm(int k) {
  return ((k >> 3) & 3) * 64 + ((k >> 5) << 3) + (k & 7);
}

// async global->LDS, 16B per lane; LDS dest = wave-uniform base + lane*16
static __device__ __forceinline__ void load_lds16(const void* g, void* l) {
  __builtin_amdgcn_global_load_lds(
      (const __attribute__((address_space(1))) unsigned int*)g,
      (__attribute__((address_space(3))) unsigned int*)l, 16, 0, 0);
}

// pack (score, idx) so u64 max == argmax with smallest-index tiebreak
static __device__ __forceinline__ unsigned long long packsi(float v, int idx) {
  unsigned int b = __float_as_uint(v);
  b = (b & 0x80000000u) ? ~b : (b | 0x80000000u);   // order-preserving map
  return ((unsigned long long)b << 32) | (unsigned int)(~(unsigned int)idx);
}

static __device__ __forceinline__ float fast_tanh(float x) {
  const float xc = fminf(fmaxf(x, -15.f), 15.f);
  const float e2 = __expf(2.f * xc);
  return 1.f - 2.f / (e2 + 1.f);
}

// LDS tile address: [kseg][row][64 shorts], 3-bit XOR chunk swizzle.
// Proven 0-conflict (R2/R4/R6) for ds_read_b128 with 16 lanes on rows.
static __device__ __forceinline__ int swadr(int kseg, int nrows, int row, int kin) {
  return (kseg * nrows + row) * 64 + (((kin >> 3) ^ (row & 7)) * 8) + (kin & 7);
}

// ---------------------------------------------------------------- fused flow (ALL 4 layers)
// One block = 16 rows, grid 512 (2 blocks/CU). SOFTWARE-PIPELINED weight
// staging: 96 segments of 16 KB, double-buffered Bs; the next segment's DMA
// is issued AFTER the barrier (so the barrier's vmcnt(0) never drains it) and
// streams during the current segment's compute -> residual wait only.
// Per layer, 24 segs: nc8 0..7 x [W1(64 h-cols, K=128) | W2(K=32 lo) | W2(K=32 hi)].
__global__ __launch_bounds__(256, 2)
void flow_all(const float* __restrict__ in,
              const unsigned short* __restrict__ W1T,   // [L][512][128]
              const unsigned short* __restrict__ W2I,   // [L][256][512] s/t interleaved
              const float* __restrict__ b1A,
              const float* __restrict__ bsA,
              const float* __restrict__ btA,
              float* __restrict__ xout,
              unsigned char* __restrict__ xf8,          // [NB][256] permuted fp8(x*SX)
              float* __restrict__ jac)
{
  __shared__ __align__(16) unsigned short Xb[2][16 * 128];   //  8 KB x-state
  __shared__ __align__(16) unsigned short Hs[16 * 64];       //  2 KB h chunk (64 cols)
  __shared__ __align__(16) unsigned short Bs[2][8192];       // 32 KB W staging (2x16KB)
  __shared__ float jlds[3][16];
  const int tid = threadIdx.x;
  const int lane = tid & 63, wave = tid >> 6;
  const int q = lane >> 4, c = lane & 15;
  const int m0 = blockIdx.x * 16;

  // issue the very first weight DMA before anything else (Bs disjoint from Xb)
  {
    const unsigned short* W1l = W1T;      // l=0, nc8=0
#pragma unroll
    for (int u = 0; u < 4; u++) {
      const int chb = (u * 4 + wave) * 64;
      const int ch = chb + lane;
      const int kseg = ch >> 9, cs = ch & 511;
      const int row = cs >> 3, cc = (cs & 7) ^ (row & 7);
      load_lds16(W1l + (size_t)row * 128 + kseg * 64 + cc * 8, Bs[0] + chb * 8);
    }
  }

  // ---- init x-state: Xb[0]=bf16(in[:, :128]) (xa0), Xb[1]=bf16(in[:,128:]) (xb0)
#pragma unroll
  for (int v = 0; v < 4; v++) {
    const int t4 = tid + v * 256;            // 1024 float4s = 16 rows x 64
    const int row = t4 >> 6, f4 = t4 & 63;
    const float4 d = *(const float4*)(in + (size_t)(m0 + row) * NF + f4 * 4);
    unsigned short* dst = Xb[f4 >> 5];
    const int feat = (f4 & 31) * 4;
    const float vals[4] = {d.x, d.y, d.z, d.w};
#pragma unroll
    for (int u = 0; u < 4; u++) {
      const int fe = feat + u;
      dst[swadr(fe >> 6, 16, row, fe & 63)] = f2bf(vals[u]);
    }
  }

  float jr[4] = {0.f, 0.f, 0.f, 0.f};
  bf16x8 af1[4];
  const f32x4 z = {0.f, 0.f, 0.f, 0.f};
  f32x4 acc2[4];

  for (int gs = 0; gs < 96; gs++) {
    __syncthreads();                          // DMA(gs) done; LDS deps settled

    // ---- prefetch segment gs+1 into the other buffer (streams under compute)
    if (gs + 1 < 96) {
      const int g2 = gs + 1;
      const int l2 = g2 / 24, s2 = g2 % 24, nc2 = s2 / 3, t2 = s2 % 3;
      unsigned short* dst = Bs[g2 & 1];
      if (t2 == 0) {
        const unsigned short* W1l = W1T + (size_t)l2 * (NHID * NHALF) + (size_t)nc2 * 64 * 128;
#pragma unroll
        for (int u = 0; u < 4; u++) {
          const int chb = (u * 4 + wave) * 64;
          const int ch = chb + lane;
          const int kseg = ch >> 9, cs = ch & 511;
          const int row = cs >> 3, cc = (cs & 7) ^ (row & 7);
          load_lds16(W1l + (size_t)row * 128 + kseg * 64 + cc * 8, dst + chb * 8);
        }
      } else {
        const unsigned short* W2l = W2I + (size_t)l2 * (NF * NHID) + nc2 * 64 + (t2 - 1) * 32;
#pragma unroll
        for (int u = 0; u < 4; u++) {
          const int chb = (u * 4 + wave) * 64;
          const int ch = chb + lane;
          const int row = ch >> 2;
          const int cc = (ch & 3) ^ ((row >> 1) & 3);
          load_lds16(W2l + (size_t)row * NHID + cc * 8, dst + chb * 8);
        }
      }
    }

    // ---- compute segment gs
    const int l = gs / 24, s = gs % 24, nc8 = s / 3, typ = s % 3;
    const unsigned short* B = Bs[gs & 1];
    unsigned short* XA = Xb[l & 1];
    unsigned short* XB = Xb[1 - (l & 1)];

    if (typ == 0) {                           // GEMM1 chunk: 64 h-cols, K=128
      if (s == 0) {                           // layer start: load A-frags, zero acc2
#pragma unroll
        for (int kw = 0; kw < 4; kw++) {
          const int kch = kw * 4 + q;
          af1[kw] = *(const bf16x8*)(XA + ((kch >> 3) * 16 + c) * 64 +
                                     (((kch & 7) ^ (c & 7)) * 8));
        }
#pragma unroll
        for (int j = 0; j < 4; j++) acc2[j] = z;
      }
      f32x4 acc1 = z;
      const int rb = wave * 16 + c;           // h-col within 64-chunk
#pragma unroll
      for (int kw = 0; kw < 4; kw++) {
        const int kseg = kw >> 1, g = (kw & 1) * 4 + q;
        const bf16x8 bf = *(const bf16x8*)(B + (kseg * 64 + rb) * 64 + ((g ^ (rb & 7)) * 8));
        acc1 = __builtin_amdgcn_mfma_f32_16x16x32_bf16(af1[kw], bf, acc1, 0, 0, 0);
      }
      const int hc = wave * 16 + c;
      const float bb = b1A[l * NHID + nc8 * 64 + hc];
#pragma unroll
      for (int r = 0; r < 4; r++) {
        float v = acc1[r] + bb;
        v = v > 0.f ? v : 0.f;
        Hs[swadr(0, 16, 4 * q + r, hc)] = f2bf(v);
      }
    } else {                                  // GEMM2: K=32 slice of this h chunk
      const int half = typ - 1;
      const bf16x8 afh = *(const bf16x8*)(Hs + c * 64 + (((half * 4 + q) ^ (c & 7)) * 8));
#pragma unroll
      for (int j = 0; j < 4; j++) {
        const int rb = wave * 64 + 16 * j + c;
        const bf16x8 bf = *(const bf16x8*)(B + rb * 32 + ((q ^ ((rb >> 1) & 3)) * 8));
        acc2[j] = __builtin_amdgcn_mfma_f32_16x16x32_bf16(afh, bf, acc2[j], 0, 0, 0);
      }
    }

    // ---- coupling epilogue at layer end (even col=s, odd col=t)
    if (s == 23) {
      const int parity = c & 1;
      const int lastl = (l == NLAY - 1);
      const float* bsl = bsA + l * NHALF;
      const float* btl = btA + l * NHALF;
#pragma unroll
      for (int j = 0; j < 4; j++) {
        const int col = wave * 64 + 16 * j + c;
#pragma unroll
        for (int r = 0; r < 4; r++) {
          const float val = acc2[j][r];
          const float oth = __shfl_xor(val, 1);   // all lanes participate
          if (!parity) {
            const int feat = col >> 1;
            float sv = val + bsl[feat];
            if (!lastl) sv = fast_tanh(sv);
            const float t = oth + btl[feat];
            const int row = 4 * q + r;
            const int xaddr = swadr(feat >> 6, 16, row, feat & 63);
            const float xb = bf2f(XB[xaddr]);
            const float yb = xb * __expf(sv) + t;
            jr[r] += sv;
            XB[xaddr] = f2bf(yb);                 // in-place: same owner thread
            if (l >= 2) {
              const int k = lastl ? feat : (NHALF + feat);
              const size_t grow = (size_t)(m0 + row) * NF;
              xout[grow + k] = yb;
              xf8[(size_t)(m0 + row) * 256 + kperm(k)] = f2fp8(yb * SX);
            }
          }
        }
      }
    }
  }

  // jac: reduce 16 c-lanes in-wave, then cross-wave via LDS (sum, not overwrite)
  float v0[4];
#pragma unroll
  for (int r = 0; r < 4; r++) {
    float v = jr[r];
    v += __shfl_xor(v, 1); v += __shfl_xor(v, 2);
    v += __shfl_xor(v, 4); v += __shfl_xor(v, 8);
    if (c == 0) {
      if (wave) jlds[wave - 1][4 * q + r] = v;
      else v0[r] = v;
    }
  }
  __syncthreads();
  if (wave == 0 && c == 0) {
#pragma unroll
    for (int r = 0; r < 4; r++) {
      const int row = 4 * q + r;
      jac[m0 + row] = v0[r] + jlds[0][row] + jlds[1][row] + jlds[2][row];
    }
  }
}

// ---------------------------------------------------------------- VQ argmax (fp8)
// Grid 512: slice = bx & 15 (XCD-pinned, 1 MB P8 slice per XCD -> L2-resident),
// m-group = bx >> 4 (256 rows). 64 register-resident fp8 X rows per wave
// (af 64 VGPR). P8 streams through ONE 16 KB LDS tile (half the bf16 traffic
// -> LDS-BW ~ MFMA balance). Layout: [64 rows][256 B], 16-chunk XOR swizzle
// cc = g ^ (row&15): 16 lanes -> 8 bank-groups x2 = 2-way = free.
__global__ __launch_bounds__(256, 2)
void vq_argmax(const unsigned char* __restrict__ X8,   // [NB][256] permuted fp8
               const unsigned char* __restrict__ P8,   // [NK][256] permuted fp8
               const float* __restrict__ nbh,          // [NK] scaled 0.5||p||^2
               unsigned long long* __restrict__ gbest) // [NB] packed
{
  __shared__ __align__(16) unsigned char Bs[64 * 256];  // 16 KB
  const int tid = threadIdx.x;
  const int lane = tid & 63, wave = tid >> 6;
  const int y = blockIdx.x & 15;
  const int m0 = (blockIdx.x >> 4) * 256;
  const int q = lane >> 4, c = lane & 15;
  const int mw = m0 + wave * 64;

  long af[4][8];
#pragma unroll
  for (int i = 0; i < 4; i++) {
    const unsigned char* xr = X8 + (size_t)(mw + 16 * i + c) * 256 + q * 64;
#pragma unroll
    for (int kc2 = 0; kc2 < 4; kc2++) {
      const i64x2 v = *(const i64x2*)(xr + kc2 * 16);
      af[i][2 * kc2] = v.x; af[i][2 * kc2 + 1] = v.y;
    }
  }

  float bestv[16];
  int besti[16];
#pragma unroll
  for (int t = 0; t < 16; t++) { bestv[t] = -1e30f; besti[t] = 0; }

  for (int nt = 0; nt < 32; nt++) {
    const int n0 = y * 2048 + nt * 64;
    if (nt) __syncthreads();
    // stage 64 codes x 256 B: slot (row,gslot) holds src chunk gslot^(row&15)
#pragma unroll
    for (int u = 0; u < 4; u++) {
      const int chb = (u * 4 + wave) * 64;
      const int ch = chb + lane;
      const int row = ch >> 4, gslot = ch & 15;
      load_lds16(P8 + (size_t)(n0 + row) * 256 + (gslot ^ (row & 15)) * 16,
                 Bs + chb * 16);
    }
    __syncthreads();

    const f32x4 z = {0.f, 0.f, 0.f, 0.f};
    f32x4 acc[4][4];
#pragma unroll
    for (int i = 0; i < 4; i++)
#pragma unroll
      for (int j = 0; j < 4; j++) acc[i][j] = z;

#pragma unroll
    for (int kc2 = 0; kc2 < 4; kc2++) {
      const int g = q * 4 + kc2;
#pragma unroll
      for (int j = 0; j < 4; j++) {
        const int rb = 16 * j + c;
        const i64x2 b2 = *(const i64x2*)(Bs + rb * 256 + ((g ^ (rb & 15)) * 16));
#pragma unroll
        for (int i = 0; i < 4; i++) {
          acc[i][j] = __builtin_amdgcn_mfma_f32_16x16x32_fp8_fp8(af[i][2 * kc2],     b2.x, acc[i][j], 0, 0, 0);
          acc[i][j] = __builtin_amdgcn_mfma_f32_16x16x32_fp8_fp8(af[i][2 * kc2 + 1], b2.y, acc[i][j], 0, 0, 0);
        }
      }
    }

    // lane-local running argmax (ascending col + strict > = lowest-index ties)
#pragma unroll
    for (int j = 0; j < 4; j++) {
      const int col = n0 + 16 * j + c;
      const float nb = nbh[col];
#pragma unroll
      for (int i = 0; i < 4; i++)
#pragma unroll
        for (int r = 0; r < 4; r++) {
          const float sc = acc[i][j][r] - nb;
          const int t = i * 4 + r;
          if (sc > bestv[t]) { bestv[t] = sc; besti[t] = col; }
        }
    }
  }

  // reduce across 16 c-lanes per slot; rows unique per (wave, i, q, r)
#pragma unroll
  for (int t = 0; t < 16; t++) {
    float lv = bestv[t]; int li = besti[t];
#pragma unroll
    for (int mk = 8; mk >= 1; mk >>= 1) {
      const float ov = __shfl_xor(lv, mk);
      const int oi = __shfl_xor(li, mk);
      if (ov > lv || (ov == lv && oi < li)) { lv = ov; li = oi; }
    }
    if (c == 0) {
      const int row = mw + 16 * (t >> 2) + q * 4 + (t & 3);
      atomicMax(&gbest[row], packsi(lv, li));
    }
  }
}

// ---------------------------------------------------------------- fused prep
// bx [0,2048): prior -> permuted fp8 (scale SP) + scaled nbh | [2048,2112):
// W1 transpose | [2112,2240): Ws/Wt -> W2I interleave | [2240,2272): init
__global__ void prep_all(const float* __restrict__ W1,
                         const float* __restrict__ Ws,
                         const float* __restrict__ Wt,
                         const float* __restrict__ prior,
                         unsigned short* __restrict__ W1T,
                         unsigned short* __restrict__ W2I,
                         unsigned char* __restrict__ p8,
                         float* __restrict__ nbh,
                         unsigned long long* __restrict__ gbest,
                         float* __restrict__ accum)
{
  __shared__ float ts[64 * 65];
  const int bx = blockIdx.x;
  const int tid = threadIdx.x;
  if (bx < 2048) {
    const int k = bx * 16 + (tid >> 4);      // code index
    const int l16 = tid & 15;
    float s = 0.f;
#pragma unroll
    for (int v = 0; v < 4; v++) {
      const int off = (v * 16 + l16) * 4;    // k-offset, multiple of 4
      const float4 d = *(const float4*)(prior + (size_t)k * NF + off);
      uchar4 o;
      o.x = f2fp8(d.x * SP); o.y = f2fp8(d.y * SP);
      o.z = f2fp8(d.z * SP); o.w = f2fp8(d.w * SP);
      *(uchar4*)(p8 + (size_t)k * 256 + kperm(off)) = o;   // 4 consec bytes
      const float q0 = fp82f(o.x), q1 = fp82f(o.y), q2 = fp82f(o.z), q3 = fp82f(o.w);
      s += q0 * q0 + q1 * q1 + q2 * q2 + q3 * q3;
    }
#pragma unroll
    for (int mk = 8; mk >= 1; mk >>= 1) s += __shfl_xor(s, mk);
    if (l16 == 0) nbh[k] = 0.5f * s * (SX / SP);   // consistent scaled domain
  } else if (bx < 2112) {
    const int job = bx - 2048;
    const int l = job >> 4, t = job & 15;
    const int k0 = (t >> 3) * 64, n0 = (t & 7) * 64;
    const float* src = W1 + (size_t)l * NHALF * NHID;
#pragma unroll
    for (int v = 0; v < 16; v++) {
      const int e = tid + v * 256;
      const int kk = e >> 6, nn = e & 63;
      ts[kk * 65 + nn] = src[(size_t)(k0 + kk) * NHID + n0 + nn];
    }
    __syncthreads();
    unsigned short* dst = W1T + (size_t)l * NHID * NHALF;
#pragma unroll
    for (int v = 0; v < 16; v++) {
      const int e = tid + v * 256;
      const int nn = e >> 6, kk = e & 63;
      dst[(size_t)(n0 + nn) * NHALF + k0 + kk] = f2bf(ts[kk * 65 + nn]);
    }
  } else if (bx < 2240) {
    const int job = bx - 2112;
    const int l = job >> 5, rem = job & 31;
    const int b = rem >> 4;
    const int k0 = ((rem >> 1) & 7) * 64;
    const int f0 = (rem & 1) * 64;
    const float* src = (b ? Wt : Ws) + (size_t)l * NHID * NHALF;
#pragma unroll
    for (int v = 0; v < 16; v++) {
      const int e = tid + v * 256;
      const int kk = e >> 6, nn = e & 63;
      ts[kk * 65 + nn] = src[(size_t)(k0 + kk) * NHALF + f0 + nn];
    }
    __syncthreads();
#pragma unroll
    for (int v = 0; v < 16; v++) {
      const int e = tid + v * 256;
      const int nn = e >> 6, kk = e & 63;
      W2I[((size_t)l * NF + 2 * (f0 + nn) + b) * NHID + k0 + kk] = f2bf(ts[kk * 65 + nn]);
    }
  } else {
    const int idx = (bx - 2240) * 256 + tid;
    if (idx < NB) gbest[idx] = 0ull;
    if (idx < 2) accum[idx] = 0.f;
  }
}

// ---------------------------------------------------------------- VQ finalize
__global__ void vq_finalize(const float* __restrict__ X,      // d_out x, fp32
                            const float* __restrict__ prior,
                            const unsigned long long* __restrict__ gbest,
                            const float* __restrict__ jac,
                            float* __restrict__ accum)        // [0]=dist,[1]=jac
{
  const int wave = threadIdx.x >> 6, lane = threadIdx.x & 63;
  const int gw = blockIdx.x * 4 + wave;        // 1024 waves, 8 rows each
  float accd = 0.f, accj = 0.f;
  for (int r = 0; r < 8; r++) {
    const int row = gw * 8 + r;
    const unsigned int idx = ~(unsigned int)(gbest[row]);   // low 32 bits = ~idx
    const float* x = X + (size_t)row * NF;
    const float* p = prior + (size_t)idx * NF;
#pragma unroll
    for (int u = 0; u < 4; u++) {
      const int d = lane + u * 64;
      const float df = x[d] - p[d];
      accd += df * df;
    }
    if (lane == 0) accj += jac[row];
  }
#pragma unroll
  for (int mk = 32; mk >= 1; mk >>= 1) {
    accd += __shfl_xor(accd, mk);
    accj += __shfl_xor(accj, mk);
  }
  __shared__ float sd[4], sj[4];
  if (lane == 0) { sd[wave] = accd; sj[wave] = accj; }
  __syncthreads();
  if (threadIdx.x == 0) {
    atomicAdd(&accum[0], sd[0] + sd[1] + sd[2] + sd[3]);
    atomicAdd(&accum[1], sj[0] + sj[1] + sj[2] + sj[3]);
  }
}

__global__ void finalize_loss(const float* __restrict__ acc, float* __restrict__ loss) {
  if (threadIdx.x == 0 && blockIdx.x == 0)
    loss[0] = 1.25f * (0.5f * acc[0] / (float)NB) - acc[1] / (float)NB;
}

// ---------------------------------------------------------------- launch
extern "C" void kernel_launch(void* const* d_in, const int* in_sizes, int n_in,
                              void* d_out, int out_size, void* d_ws, size_t ws_size,
                              hipStream_t stream)
{
  (void)in_sizes; (void)n_in; (void)out_size; (void)ws_size;
  const float* inputs = (const float*)d_in[0];
  const float* W1 = (const float*)d_in[1];
  const float* b1 = (const float*)d_in[2];
  const float* Ws = (const float*)d_in[3];
  const float* bs = (const float*)d_in[4];
  const float* Wt = (const float*)d_in[5];
  const float* bt = (const float*)d_in[6];
  const float* prior = (const float*)d_in[7];

  char* p = (char*)d_ws;
  auto alloc = [&](size_t bytes) { char* r = p; p += (bytes + 255) & ~(size_t)255; return r; };
  unsigned short* W1T  = (unsigned short*)alloc((size_t)NLAY * NHID * NHALF * 2);
  unsigned short* W2I  = (unsigned short*)alloc((size_t)NLAY * NF * NHID * 2);
  unsigned char* P8    = (unsigned char*)alloc((size_t)NK * 256);
  float* NBH           = (float*)alloc((size_t)NK * 4);
  unsigned char* XF8   = (unsigned char*)alloc((size_t)NB * 256);
  float* JAC           = (float*)alloc((size_t)NB * 4);
  unsigned long long* GBEST = (unsigned long long*)alloc((size_t)NB * 8);
  float* ACC           = (float*)alloc(256);

  float* xout = (float*)d_out;                 // [NB][NF]
  float* loss = xout + (size_t)NB * NF;        // scalar

  prep_all<<<dim3(2272), 256, 0, stream>>>(
      W1, Ws, Wt, prior, W1T, W2I, P8, NBH, GBEST, ACC);

  flow_all<<<dim3(NB / 16), 256, 0, stream>>>(
      inputs, W1T, W2I, b1, bs, bt, xout, XF8, JAC);

  vq_argmax<<<dim3(32 * 16), 256, 0, stream>>>(XF8, P8, NBH, GBEST);
  vq_finalize<<<dim3(256), 256, 0, stream>>>(xout, prior, GBEST, JAC, ACC);
  finalize_loss<<<1, 1, 0, stream>>>(ACC, loss);
}